// Round 7
// baseline (2877.891 us; speedup 1.0000x reference)
//
#include <hip/hip_runtime.h>
#include <math.h>

// Problem constants (from reference)
#define Bn    256
#define Tn    1024
#define In    64
#define Pn    256
#define En    128
#define NOUTn 64
#define LN_EPS 1e-5f

// softmax factorization constants (TEMP=8):
#define C1f 0.3606737602222409f     // log2(e)/4
#define K1f 0.8824969025845955f     // exp(-1/8)
#define K2f 0.6065306597126334f     // exp(-4/8)

typedef float f32x2 __attribute__((ext_vector_type(2)));

__device__ __forceinline__ float tanh_fast(float x) {
    float e = __builtin_amdgcn_exp2f(x * 2.88539008177793f);   // e^(2x)
    return 1.0f - 2.0f * __builtin_amdgcn_rcpf(e + 1.0f);
}
__device__ __forceinline__ f32x2 tanh2(f32x2 x) {
    f32x2 e;
    e[0] = __builtin_amdgcn_exp2f(x[0] * 2.88539008177793f);
    e[1] = __builtin_amdgcn_exp2f(x[1] * 2.88539008177793f);
    f32x2 r;
    r[0] = __builtin_amdgcn_rcpf(e[0] + 1.0f);
    r[1] = __builtin_amdgcn_rcpf(e[1] + 1.0f);
    return 1.0f - 2.0f * r;
}

template<int CTRL, int RMASK>
__device__ __forceinline__ float dpp_add(float x) {
    return x + __int_as_float(__builtin_amdgcn_update_dpp(
        0, __float_as_int(x), CTRL, RMASK, 0xF, false));
}
__device__ __forceinline__ void wave_sum64_x3(float& x, float& y, float& z) {
#define LVL(C, R) x = dpp_add<C, R>(x); y = dpp_add<C, R>(y); z = dpp_add<C, R>(z);
    LVL(0x111, 0xF)
    LVL(0x112, 0xF)
    LVL(0x114, 0xF)
    LVL(0x118, 0xF)
    LVL(0x142, 0xA)
    LVL(0x143, 0xC)
#undef LVL
    x = __int_as_float(__builtin_amdgcn_readlane(__float_as_int(x), 63));
    y = __int_as_float(__builtin_amdgcn_readlane(__float_as_int(y), 63));
    z = __int_as_float(__builtin_amdgcn_readlane(__float_as_int(z), 63));
}

// ===========================================================================
// R15: ISOLATION DIAGNOSTIC. Two phase-isolation microbench kernels (8192
// dependent iterations each -> both slower than the real kernel, so the
// slower one is identified BY NAME in the top-5; the other is recovered from
// the bench-total sum). Real kernel = R12 verbatim (best, 392us), runs last.
//   chain_iso: non-LDS recurrence chain (ctx FMAs -> tanh2 -> pair sums ->
//              6-level DPP x3 -> readlane -> LN -> hid -> gate branch)
//   ldsrt_iso: ring LDS round-trip chain (5 ds_write -> program-order
//              dependent ds_read of an untouched row + jd read -> carry)
// ===========================================================================

#define ISO_ITERS 8192

__global__ __launch_bounds__(64, 1)
void chain_iso(const float* __restrict__ x,
               const float* __restrict__ Wg, const float* __restrict__ bg,
               const float* __restrict__ ln_w, const float* __restrict__ ln_b,
               float* __restrict__ out) {
    const int l = threadIdx.x;
    const int b = blockIdx.x;
    const f32x2 lnw = {ln_w[l], ln_w[l + 64]};
    const f32x2 lnb = {ln_b[l], ln_b[l + 64]};
    const f32x2 wg  = {Wg[l],   Wg[l + 64]};
    const float bgs = bg[0];
    f32x2 em;  em[0] = 0.003f * (float)l; em[1] = -0.002f * (float)l;
    f32x2 hid; hid[0] = x[b * 64 + l] * 1e-3f; hid[1] = 0.f;
    float jl = 0.f;

    #pragma unroll 1
    for (int i = 0; i < ISO_ITERS; ++i) {
        // ctx surrogate: 4 dependent FMAs from hid (mirrors ctxWp length)
        f32x2 c1 = hid * 0.11f + em;
        f32x2 c2 = c1 * 0.13f + hid;
        f32x2 c3 = c2 * 0.17f + em;
        const f32x2 ctx = c3 * 0.19f;
        const f32x2 su = tanh2(em + 0.55f * ctx + hid);
        float s1 = su[0] + su[1];
        const f32x2 sq = su * su;  float s2 = sq[0] + sq[1];
        const f32x2 sg = su * wg;  float s3 = sg[0] + sg[1];
        wave_sum64_x3(s1, s2, s3);
        const float mu   = s1 * (1.0f / En);
        const float var  = s2 * (1.0f / En) - mu * mu;
        const float rstd = __builtin_amdgcn_rsqf(var + LN_EPS);
        hid = (su - mu) * rstd * lnw + lnb;
        jl  = s3 + bgs;
        // wave-uniform gate branch (readfirstlane -> SALU -> branch hazard)
        if (__builtin_amdgcn_readfirstlane(__float_as_int(jl)) > 0)
            hid[0] = hid[0] + 1e-7f;
    }
    out[b * NOUTn + l] = hid[0] + hid[1] + jl;
}

#define ISO_LDS_FLOATS (Pn * En + Pn)        // 33024
#define ISO_LDS_BYTES  (ISO_LDS_FLOATS * 4)  // 132096

__global__ __launch_bounds__(64, 1)
void ldsrt_iso(const float* __restrict__ x,
               const float* __restrict__ jump_dest,
               float* __restrict__ out) {
    extern __shared__ float lds[];
    float* mem = lds;
    float* jd  = lds + Pn * En;
    const int l = threadIdx.x;
    const int b = blockIdx.x;

    const float seed = x[b * 64 + l] * 1e-3f;
    float4* m4 = (float4*)mem;
    for (int i = l; i < Pn * En / 4; i += 64)
        m4[i] = make_float4(seed, seed * 0.5f, 0.f, 0.f);
    for (int i = l; i < Pn; i += 64) jd[i] = jump_dest[i];
    __syncthreads();

    f32x2 v; v[0] = mem[2 * l]; v[1] = mem[2 * l + 1];
    int base = 0;

    #pragma unroll 1
    for (int i = 0; i < ISO_ITERS; ++i) {
        float* p0 = mem + ((base & 255) << 7) + 2 * l;
        float* p1 = mem + (((base + 1) & 255) << 7) + 2 * l;
        float* p2 = mem + (((base + 2) & 255) << 7) + 2 * l;
        float* p3 = mem + (((base + 3) & 255) << 7) + 2 * l;
        float* p4 = mem + (((base + 4) & 255) << 7) + 2 * l;
        // scatter values derived from the carried register (mirrors m_v)
        const f32x2 m0 = v + 0.01f, m1 = v + 0.02f, m2 = v + 0.03f,
                    m3 = v + 0.04f, m4v = v + 0.05f;
        *(f32x2*)p0 = m0; *(f32x2*)p1 = m1; *(f32x2*)p2 = m2;
        *(f32x2*)p3 = m3; *(f32x2*)p4 = m4v;
        // dependent read, program-order AFTER the writes (row base+5 is not
        // in this iter's scatter set -- exactly the wnb4 pattern)
        float* q = mem + (((base + 5) & 255) << 7) + 2 * l;
        const f32x2 r = *(f32x2*)q;
        const float jt = jd[(base + 1) & 255];
        v = r * 0.999f;                 // carry: read -> next iter's writes
        v[0] += jt * 1e-9f;
        base = (base + 1) & 255;
    }
    out[b * NOUTn + l] = v[0] + v[1];
}

// ======================= REAL KERNEL: R12 verbatim =========================
#define STAGE_FLOATS (3 * 16 * En)                 // 6144
#define LDSF_FLOATS  (Pn * En + Pn + STAGE_FLOATS) // 39168
#define LDSF_BYTES   (LDSF_FLOATS * 4)             // 156672

__global__ __launch_bounds__(192, 1)
void fused2_kernel(const float* __restrict__ x,
                   const float* __restrict__ pointer_init,
                   const float* __restrict__ W_in, const float* __restrict__ b_in,
                   const float* __restrict__ ln_w, const float* __restrict__ ln_b,
                   const float* __restrict__ jump_dest,
                   const float* __restrict__ Wg,  const float* __restrict__ bg,
                   const float* __restrict__ cs_ptr,
                   const float* __restrict__ Wo,  const float* __restrict__ bo,
                   float* __restrict__ out) {
    extern __shared__ float lds[];
    float* mem = lds;                    // ring: [row][2*l + c]
    float* jd  = lds + Pn * En;          // jump_dest copy
    float* stg = lds + Pn * En + Pn;     // stage: [buf3][tq4][e128][t4]

    const int b   = blockIdx.x;
    const int tid = threadIdx.x;

    if (tid >= 64) {
        // ================= PRODUCERS (waves 1,2): 4t x 4e register tile ======
        const int p    = tid - 64;        // 0..127
        const int tq   = p >> 5;          // 0..3 : which 4-t group of the chunk
        const int eidx = p & 31;          // e = eidx + 32*j, j=0..3
        float be[4];
        #pragma unroll
        for (int j = 0; j < 4; ++j) be[j] = b_in[eidx + 32 * j];
        const float* xb = x + (size_t)b * Tn * In;

#define PRODUCE(K, BUF) {                                                     \
    const int t0 = (K) * 16 + tq * 4;                                         \
    const float4* xr = (const float4*)(xb + t0 * In);   /* per-lane addr */   \
    float acc[4][4];                                                          \
    _Pragma("unroll")                                                         \
    for (int tt = 0; tt < 4; ++tt)                                            \
        _Pragma("unroll")                                                     \
        for (int j = 0; j < 4; ++j) acc[tt][j] = 0.f;                         \
    _Pragma("unroll")                                                         \
    for (int i4 = 0; i4 < 16; ++i4) {                                         \
        float4 xv[4];                                                         \
        _Pragma("unroll")                                                     \
        for (int tt = 0; tt < 4; ++tt) xv[tt] = xr[tt * 16 + i4];             \
        float4 wf[4];                                                         \
        _Pragma("unroll")                                                     \
        for (int j = 0; j < 4; ++j)                                           \
            wf[j] = *(const float4*)(W_in + (eidx + 32 * j) * In + i4 * 4);   \
        _Pragma("unroll")                                                     \
        for (int tt = 0; tt < 4; ++tt)                                        \
            _Pragma("unroll")                                                 \
            for (int j = 0; j < 4; ++j) {                                     \
                acc[tt][j] += xv[tt].x * wf[j].x;                             \
                acc[tt][j] += xv[tt].y * wf[j].y;                             \
                acc[tt][j] += xv[tt].z * wf[j].z;                             \
                acc[tt][j] += xv[tt].w * wf[j].w;                             \
            }                                                                 \
    }                                                                         \
    float* sg = stg + (BUF) * 2048 + tq * 512;                                \
    _Pragma("unroll")                                                         \
    for (int j = 0; j < 4; ++j) {                                             \
        float4 o;                                                             \
        o.x = tanh_fast(acc[0][j] + be[j]);                                   \
        o.y = tanh_fast(acc[1][j] + be[j]);                                   \
        o.z = tanh_fast(acc[2][j] + be[j]);                                   \
        o.w = tanh_fast(acc[3][j] + be[j]);                                   \
        *(float4*)(sg + (eidx + 32 * j) * 4) = o;                             \
    }                                                                         \
}
        PRODUCE(0, 0)
        PRODUCE(1, 1)
        __syncthreads();                   // #1: chunks 0,1 staged
        int buf = 2;
        for (int k = 0; k < 64; ++k) {
            if (k + 2 < 64) {
                PRODUCE(k + 2, buf)
                buf = (buf == 2) ? 0 : buf + 1;
            }
            __syncthreads();               // chunk boundary
        }
#undef PRODUCE
        __syncthreads();                   // final: hid broadcast
        return;
    }

    // ================= CONSUMER (wave 0): scan, LDS-staged emb ==============
    const int l = tid;

    float4* m4 = (float4*)mem;
    for (int i = l; i < Pn * En / 4; i += 64) m4[i] = make_float4(0.f, 0.f, 0.f, 0.f);
    for (int i = l; i < Pn; i += 64) jd[i] = jump_dest[i];

    const f32x2 lnw = {ln_w[l], ln_w[l + 64]};
    const f32x2 lnb = {ln_b[l], ln_b[l + 64]};
    const f32x2 wg  = {Wg[l],   Wg[l + 64]};
    const float bgs = bg[0];
    const float cs  = 1.0f / (1.0f + expf(-cs_ptr[0]));
    f32x2 hid = {0.f, 0.f};

    float* myb = mem + 2 * l;

    // ---- pipeline state (forced jump to pointer_init at t=0) ----
    float jl      = 1.0f;
    float jt_cur  = pointer_init[b];
    float ptrW    = 0.f;
    int   baseW   = 0;
    float jtW_pre = 0.f;
    float z0 = 0.f, z1 = 0.f, z2 = 1.f, z3 = 0.f, z4 = 0.f, inv = 1.f;
    f32x2 wnb0 = {0,0}, wnb1 = {0,0}, wnb2 = {0,0}, wnb3 = {0,0}, wnb4 = {0,0};
    float *wp0 = myb, *wp1 = myb, *wp2 = myb, *wp3 = myb, *wp4 = myb;
    f32x2 ctxWp = {0.f, 0.f};              // walk-path ctx, precomputed at tail

    __syncthreads();                       // #1: emb chunks 0,1 staged
    __builtin_amdgcn_s_setprio(1);         // favor the serial wave

    // A = current 4-step group registers (group tb=0)
    const float* sa0 = stg + 4 * l;        // buf0, group 0, ch l
    float4 A0 = *(const float4*)sa0;
    float4 A1 = *(const float4*)(sa0 + 256);

#define SSTEP(EC0, EC1) {                                                      \
    float ptr; int base;                                                       \
    f32x2 nb0, nb1, nb2, nb3, nb4;                                             \
    float *p0, *p1, *p2, *p3, *p4;                                             \
    float jt_nxt;                                                              \
    f32x2 ctx;                                                                 \
    if (__builtin_amdgcn_readfirstlane(__float_as_int(jl)) > 0) {              \
        /* JUMP: full gather (issued first) + weight recompute */              \
        ptr  = jt_cur;                                                         \
        base = (int)ptr; base = base > 255 ? 255 : base;                       \
        p0 = mem + (((base + 254) & 255) << 7) + 2 * l;                        \
        p1 = mem + (((base + 255) & 255) << 7) + 2 * l;                        \
        p2 = mem + (base << 7) + 2 * l;                                        \
        p3 = mem + (((base + 1) & 255) << 7) + 2 * l;                          \
        p4 = mem + (((base + 2) & 255) << 7) + 2 * l;                          \
        nb0 = *(f32x2*)p0; nb1 = *(f32x2*)p1; nb2 = *(f32x2*)p2;               \
        nb3 = *(f32x2*)p3; nb4 = *(f32x2*)p4;                                  \
        jt_nxt = jd[base];                                                     \
        const float frac = ptr - (float)base;                                  \
        const float r  = __builtin_amdgcn_exp2f(frac * C1f);                   \
        const float ri = __builtin_amdgcn_exp2f(-frac * C1f);                  \
        z0 = K2f * ri * ri; z1 = K1f * ri; z2 = 1.0f;                          \
        z3 = K1f * r;       z4 = K2f * r * r;                                  \
        inv = __builtin_amdgcn_rcpf(((z0 + z1) + (z2 + z3)) + z4);             \
        ctx = inv * (((nb0 * z0 + nb1 * z1) + (nb2 * z2 + nb3 * z3))           \
                     + nb4 * z4);                                              \
    } else {                                                                   \
        /* WALK: weights carried; ctx PRECOMPUTED last step (same bits) */     \
        ptr = ptrW; base = baseW;                                              \
        nb0 = wnb0; nb1 = wnb1; nb2 = wnb2; nb3 = wnb3; nb4 = wnb4;            \
        p0 = wp0; p1 = wp1; p2 = wp2; p3 = wp3; p4 = wp4;                      \
        jt_nxt = jtW_pre;                                                      \
        ctx = ctxWp;                                                           \
    }                                                                          \
    f32x2 em; em[0] = (EC0); em[1] = (EC1);                                    \
    const f32x2 su = tanh2(em + cs * ctx + hid);                               \
    /* HOISTED reduce: tree issues immediately; scatter/prep run under it */   \
    float s1 = su[0] + su[1];                                                  \
    const f32x2 sq = su * su;  float s2 = sq[0] + sq[1];                       \
    const f32x2 sg = su * wg;  float s3 = sg[0] + sg[1];                       \
    wave_sum64_x3(s1, s2, s3);                                                 \
    /* scatter + next-walk prep (independent of tree) */                       \
    const f32x2 g  = su * inv;                                                 \
    const f32x2 m0v = nb0 + z0 * g, m1v = nb1 + z1 * g, m2v = nb2 + z2 * g,    \
                m3v = nb3 + z3 * g, m4v = nb4 + z4 * g;                        \
    *(f32x2*)p0 = m0v; *(f32x2*)p1 = m1v; *(f32x2*)p2 = m2v;                   \
    *(f32x2*)p3 = m3v; *(f32x2*)p4 = m4v;                                      \
    baseW = (base + 1) & 255;                                                  \
    ptrW  = ptr + 1.0f; if (ptrW >= 256.0f) ptrW -= 256.0f;                    \
    wnb0 = m1v; wnb1 = m2v; wnb2 = m3v; wnb3 = m4v;                            \
    wp0 = p1; wp1 = p2; wp2 = p3; wp3 = p4;                                    \
    wp4 = mem + (((base + 3) & 255) << 7) + 2 * l;                             \
    wnb4 = *(f32x2*)wp4;                                                       \
    jtW_pre = jd[baseW];                                                       \
    jt_cur  = jt_nxt;                                                          \
    ctxWp = inv * (((wnb0 * z0 + wnb1 * z1) + (wnb2 * z2 + wnb3 * z3))         \
                   + wnb4 * z4);                                               \
    /* LN + gate */                                                            \
    const float mu   = s1 * (1.0f / En);                                       \
    const float var  = s2 * (1.0f / En) - mu * mu;                             \
    const float rstd = __builtin_amdgcn_rsqf(var + LN_EPS);                    \
    hid = (su - mu) * rstd * lnw + lnb;                                        \
    jl  = s3 + bgs;                                                            \
}

    for (int k = 0; k < 64; ++k) {
        #pragma unroll
        for (int g = 0; g < 4; ++g) {
            const int tb  = k * 4 + g;
            int tbn = tb + 1; if (tbn > 255) tbn = 255;
            // prefetch next group: buf[(tbn>>2)%3] is never producer-active
            const float* sb = stg + ((tbn >> 2) % 3) * 2048 + (tbn & 3) * 512 + 4 * l;
            float4 B0 = *(const float4*)sb;
            float4 B1 = *(const float4*)(sb + 256);
            SSTEP(A0.x, A1.x)
            SSTEP(A0.y, A1.y)
            SSTEP(A0.z, A1.z)
            SSTEP(A0.w, A1.w)
            A0 = B0; A1 = B1;
        }
        __syncthreads();               // chunk boundary (chunk k+2 staged)
    }
#undef SSTEP

    // epilogue: logits = hid @ Wo^T + bo
    __builtin_amdgcn_s_setprio(0);
    mem[l] = hid[0]; mem[64 + l] = hid[1];
    __syncthreads();                   // final
    const float4* w4 = (const float4*)(Wo + l * En);
    const float4* h4 = (const float4*)mem;
    float a0 = 0.f, a1 = 0.f, a2 = 0.f, a3 = 0.f;
    #pragma unroll
    for (int i = 0; i < En / 4; ++i) {
        float4 wv = w4[i]; float4 hv = h4[i];
        a0 += wv.x * hv.x; a1 += wv.y * hv.y; a2 += wv.z * hv.z; a3 += wv.w * hv.w;
    }
    out[b * NOUTn + l] = (a0 + a1) + (a2 + a3) + bo[l];
}

extern "C" void kernel_launch(void* const* d_in, const int* in_sizes, int n_in,
                              void* d_out, int out_size, void* d_ws, size_t ws_size,
                              hipStream_t stream) {
    const float* x            = (const float*)d_in[0];
    const float* pointer_init = (const float*)d_in[1];
    const float* W_in         = (const float*)d_in[2];
    const float* b_in         = (const float*)d_in[3];
    const float* ln_w         = (const float*)d_in[4];
    const float* ln_b         = (const float*)d_in[5];
    const float* jump_dest    = (const float*)d_in[6];
    const float* Wg           = (const float*)d_in[7];
    const float* bg           = (const float*)d_in[8];
    const float* cs           = (const float*)d_in[9];
    const float* Wo           = (const float*)d_in[10];
    const float* bo           = (const float*)d_in[11];
    float* out = (float*)d_out;
    (void)d_ws; (void)ws_size;

    // ---- isolation diagnostics (outputs overwritten by the real kernel) ----
    chain_iso<<<Bn, 64, 0, stream>>>(x, Wg, bg, ln_w, ln_b, out);
    (void)hipFuncSetAttribute((const void*)ldsrt_iso,
                              hipFuncAttributeMaxDynamicSharedMemorySize, ISO_LDS_BYTES);
    ldsrt_iso<<<Bn, 64, ISO_LDS_BYTES, stream>>>(x, jump_dest, out);

    // ---- real kernel (R12, best measured) ----
    (void)hipFuncSetAttribute((const void*)fused2_kernel,
                              hipFuncAttributeMaxDynamicSharedMemorySize, LDSF_BYTES);
    fused2_kernel<<<Bn, 192, LDSF_BYTES, stream>>>(
        x, pointer_init, W_in, b_in, ln_w, ln_b, jump_dest, Wg, bg, cs,
        Wo, bo, out);
}

// Round 8
// 514.845 us; speedup vs baseline: 5.5898x; 5.5898x over previous
//
#include <hip/hip_runtime.h>
#include <math.h>

// Problem constants (from reference)
#define Bn    256
#define Tn    1024
#define In    64
#define Pn    256
#define En    128
#define NOUTn 64
#define LN_EPS 1e-5f

// softmax factorization constants (TEMP=8):
// z_j ∝ exp((j-2)*frac/4) * exp(-(j-2)^2/8)  (common exp(-frac^2/8) cancels)
#define C1f 0.3606737602222409f     // log2(e)/4
#define K1f 0.8824969025845955f     // exp(-1/8)
#define K2f 0.6065306597126334f     // exp(-4/8)

typedef float f32x2 __attribute__((ext_vector_type(2)));

__device__ __forceinline__ float tanh_fast(float x) {
    float e = __builtin_amdgcn_exp2f(x * 2.88539008177793f);   // e^(2x)
    return 1.0f - 2.0f * __builtin_amdgcn_rcpf(e + 1.0f);
}
__device__ __forceinline__ f32x2 tanh2(f32x2 x) {
    f32x2 e;
    e[0] = __builtin_amdgcn_exp2f(x[0] * 2.88539008177793f);
    e[1] = __builtin_amdgcn_exp2f(x[1] * 2.88539008177793f);
    f32x2 r;
    r[0] = __builtin_amdgcn_rcpf(e[0] + 1.0f);
    r[1] = __builtin_amdgcn_rcpf(e[1] + 1.0f);
    return 1.0f - 2.0f * r;
}

template<int CTRL, int RMASK>
__device__ __forceinline__ float dpp_add(float x) {
    return x + __int_as_float(__builtin_amdgcn_update_dpp(
        0, __float_as_int(x), CTRL, RMASK, 0xF, false));
}
__device__ __forceinline__ void wave_sum64_x3(float& x, float& y, float& z) {
#define LVL(C, R) x = dpp_add<C, R>(x); y = dpp_add<C, R>(y); z = dpp_add<C, R>(z);
    LVL(0x111, 0xF)
    LVL(0x112, 0xF)
    LVL(0x114, 0xF)
    LVL(0x118, 0xF)
    LVL(0x142, 0xA)
    LVL(0x143, 0xC)
#undef LVL
    x = __int_as_float(__builtin_amdgcn_readlane(__float_as_int(x), 63));
    y = __int_as_float(__builtin_amdgcn_readlane(__float_as_int(y), 63));
    z = __int_as_float(__builtin_amdgcn_readlane(__float_as_int(z), 63));
}

// ===========================================================================
// R16: DS-OP DIET (from R15 isolation: arithmetic chain = 422 cy/step; each
// DS op costs ~35 cy of effectively-serial time at 1 wave; real step 846 cy
// ≈ 422 + 12 DS ops x 35. All prior restructurings kept the DS count and
// landed at 392-410 us).
//
// Changes vs R12 (all bit-exact):
//  1. DEFERRED-EVICT REGISTER WINDOW: the 5-row window lives in regs
//     (wnb0..4, already carried). Per walk step only ONE row leaves the
//     window -> write only that row (1 ds_write_b64 instead of 5). Dirty
//     invariant: wnb0..3 dirty in regs, wnb4 clean (just read). On a jump
//     step, flush wnb0..3 BEFORE the gather -- the in-order DS pipe makes
//     the gather see them, so any LDS read returns exactly what the
//     full-scatter version would have written.
//  2. jump_dest reads moved OFF the DS pipe: per-lane global loads (vmcnt,
//     same address all lanes -> one L2 line; consumed >= 1 full step later
//     -> latency hidden). LDS jd copy deleted.
//  3. sched_barrier(0) after the evict-write + incoming-read issue, pinning
//     them ahead of the reduce tree so the LDS latency hides under it.
// DS ops/step: walk 7 -> 2; jump ~12 (4 flush + 5 gather + evict + read).
// LDS: ring 128 KB + stage 24 KB = 152 KB.
// ===========================================================================
#define STAGE_FLOATS (3 * 16 * En)              // 6144
#define LDSF_FLOATS  (Pn * En + STAGE_FLOATS)   // 38912
#define LDSF_BYTES   (LDSF_FLOATS * 4)          // 155648

__global__ __launch_bounds__(192, 1)
void fused2_kernel(const float* __restrict__ x,
                   const float* __restrict__ pointer_init,
                   const float* __restrict__ W_in, const float* __restrict__ b_in,
                   const float* __restrict__ ln_w, const float* __restrict__ ln_b,
                   const float* __restrict__ jump_dest,
                   const float* __restrict__ Wg,  const float* __restrict__ bg,
                   const float* __restrict__ cs_ptr,
                   const float* __restrict__ Wo,  const float* __restrict__ bo,
                   float* __restrict__ out) {
    extern __shared__ float lds[];
    float* mem = lds;                    // ring: [row][2*l + c]
    float* stg = lds + Pn * En;          // stage: [buf3][tq4][e128][t4]

    const int b   = blockIdx.x;
    const int tid = threadIdx.x;

    if (tid >= 64) {
        // ================= PRODUCERS (waves 1,2): 4t x 4e register tile ======
        const int p    = tid - 64;        // 0..127
        const int tq   = p >> 5;          // 0..3 : which 4-t group of the chunk
        const int eidx = p & 31;          // e = eidx + 32*j, j=0..3
        float be[4];
        #pragma unroll
        for (int j = 0; j < 4; ++j) be[j] = b_in[eidx + 32 * j];
        const float* xb = x + (size_t)b * Tn * In;

#define PRODUCE(K, BUF) {                                                     \
    const int t0 = (K) * 16 + tq * 4;                                         \
    const float4* xr = (const float4*)(xb + t0 * In);   /* per-lane addr */   \
    float acc[4][4];                                                          \
    _Pragma("unroll")                                                         \
    for (int tt = 0; tt < 4; ++tt)                                            \
        _Pragma("unroll")                                                     \
        for (int j = 0; j < 4; ++j) acc[tt][j] = 0.f;                         \
    _Pragma("unroll")                                                         \
    for (int i4 = 0; i4 < 16; ++i4) {                                         \
        float4 xv[4];                                                         \
        _Pragma("unroll")                                                     \
        for (int tt = 0; tt < 4; ++tt) xv[tt] = xr[tt * 16 + i4];             \
        float4 wf[4];                                                         \
        _Pragma("unroll")                                                     \
        for (int j = 0; j < 4; ++j)                                           \
            wf[j] = *(const float4*)(W_in + (eidx + 32 * j) * In + i4 * 4);   \
        _Pragma("unroll")                                                     \
        for (int tt = 0; tt < 4; ++tt)                                        \
            _Pragma("unroll")                                                 \
            for (int j = 0; j < 4; ++j) {                                     \
                acc[tt][j] += xv[tt].x * wf[j].x;                             \
                acc[tt][j] += xv[tt].y * wf[j].y;                             \
                acc[tt][j] += xv[tt].z * wf[j].z;                             \
                acc[tt][j] += xv[tt].w * wf[j].w;                             \
            }                                                                 \
    }                                                                         \
    float* sg = stg + (BUF) * 2048 + tq * 512;                                \
    _Pragma("unroll")                                                         \
    for (int j = 0; j < 4; ++j) {                                             \
        float4 o;                                                             \
        o.x = tanh_fast(acc[0][j] + be[j]);                                   \
        o.y = tanh_fast(acc[1][j] + be[j]);                                   \
        o.z = tanh_fast(acc[2][j] + be[j]);                                   \
        o.w = tanh_fast(acc[3][j] + be[j]);                                   \
        *(float4*)(sg + (eidx + 32 * j) * 4) = o;                             \
    }                                                                         \
}
        PRODUCE(0, 0)
        PRODUCE(1, 1)
        __syncthreads();                   // #1: chunks 0,1 staged
        int buf = 2;
        for (int k = 0; k < 64; ++k) {
            if (k + 2 < 64) {
                PRODUCE(k + 2, buf)
                buf = (buf == 2) ? 0 : buf + 1;
            }
            __syncthreads();               // chunk boundary
        }
#undef PRODUCE
        __syncthreads();                   // final: hid broadcast
        return;
    }

    // ================= CONSUMER (wave 0): deferred-evict scan ===============
    const int l = tid;

    float4* m4 = (float4*)mem;
    for (int i = l; i < Pn * En / 4; i += 64) m4[i] = make_float4(0.f, 0.f, 0.f, 0.f);

    const f32x2 lnw = {ln_w[l], ln_w[l + 64]};
    const f32x2 lnb = {ln_b[l], ln_b[l + 64]};
    const f32x2 wg  = {Wg[l],   Wg[l + 64]};
    const float bgs = bg[0];
    const float cs  = 1.0f / (1.0f + expf(-cs_ptr[0]));
    f32x2 hid = {0.f, 0.f};

    float* myb = mem + 2 * l;

    // ---- pipeline state (forced jump to pointer_init at t=0) ----
    float jl      = 1.0f;
    float jt_cur  = pointer_init[b];
    float ptrW    = 0.f;
    int   baseW   = 0;
    float jtW_pre = 0.f;
    float z0 = 0.f, z1 = 0.f, z2 = 1.f, z3 = 0.f, z4 = 0.f, inv = 1.f;
    // register window: wnb0..3 DIRTY (deferred writes), wnb4 CLEAN.
    // initial dummy window: zeros at row 0 -> a flush writes 0 over 0 (ok).
    f32x2 wnb0 = {0,0}, wnb1 = {0,0}, wnb2 = {0,0}, wnb3 = {0,0}, wnb4 = {0,0};
    float *wp0 = myb, *wp1 = myb, *wp2 = myb, *wp3 = myb, *wp4 = myb;
    f32x2 ctxWp = {0.f, 0.f};              // walk-path ctx, precomputed at tail

    __syncthreads();                       // #1: mem zeroed, stage chunks 0,1
    __builtin_amdgcn_s_setprio(1);         // favor the serial wave

    // A = current 4-step group registers (group tb=0)
    const float* sa0 = stg + 4 * l;        // buf0, group 0, ch l
    float4 A0 = *(const float4*)sa0;
    float4 A1 = *(const float4*)(sa0 + 256);

#define SSTEP(EC0, EC1) {                                                      \
    float ptr; int base;                                                       \
    f32x2 nb0, nb1, nb2, nb3, nb4;                                             \
    float *p0, *p1, *p2, *p3, *p4;                                             \
    float jt_nxt;                                                              \
    f32x2 ctx;                                                                 \
    if (__builtin_amdgcn_readfirstlane(__float_as_int(jl)) > 0) {              \
        /* JUMP: flush dirty rows FIRST (in-order DS => gather sees them,     \
           bit-identical to the full-scatter version), then gather. */         \
        *(f32x2*)wp0 = wnb0; *(f32x2*)wp1 = wnb1;                              \
        *(f32x2*)wp2 = wnb2; *(f32x2*)wp3 = wnb3;                              \
        ptr  = jt_cur;                                                         \
        base = (int)ptr; base = base > 255 ? 255 : base;                       \
        p0 = mem + (((base + 254) & 255) << 7) + 2 * l;                        \
        p1 = mem + (((base + 255) & 255) << 7) + 2 * l;                        \
        p2 = mem + (base << 7) + 2 * l;                                        \
        p3 = mem + (((base + 1) & 255) << 7) + 2 * l;                          \
        p4 = mem + (((base + 2) & 255) << 7) + 2 * l;                          \
        nb0 = *(f32x2*)p0; nb1 = *(f32x2*)p1; nb2 = *(f32x2*)p2;               \
        nb3 = *(f32x2*)p3; nb4 = *(f32x2*)p4;                                  \
        jt_nxt = jump_dest[base];         /* global load (vmcnt, same addr */  \
        const float frac = ptr - (float)base;   /* all lanes -> 1 L2 line) */  \
        const float r  = __builtin_amdgcn_exp2f(frac * C1f);                   \
        const float ri = __builtin_amdgcn_exp2f(-frac * C1f);                  \
        z0 = K2f * ri * ri; z1 = K1f * ri; z2 = 1.0f;                          \
        z3 = K1f * r;       z4 = K2f * r * r;                                  \
        inv = __builtin_amdgcn_rcpf(((z0 + z1) + (z2 + z3)) + z4);             \
        ctx = inv * (((nb0 * z0 + nb1 * z1) + (nb2 * z2 + nb3 * z3))           \
                     + nb4 * z4);                                              \
    } else {                                                                   \
        /* WALK: window+weights carried in regs; ctx precomputed at tail */    \
        ptr = ptrW; base = baseW;                                              \
        nb0 = wnb0; nb1 = wnb1; nb2 = wnb2; nb3 = wnb3; nb4 = wnb4;            \
        p0 = wp0; p1 = wp1; p2 = wp2; p3 = wp3; p4 = wp4;                      \
        jt_nxt = jtW_pre;                                                      \
        ctx = ctxWp;                                                           \
    }                                                                          \
    /* incoming row read: row base+3 is outside the window & clean in LDS;    \
       issued early so its latency hides under the reduce tree. */             \
    float* wp4n = mem + (((base + 3) & 255) << 7) + 2 * l;                     \
    const f32x2 wnb4n = *(f32x2*)wp4n;                                         \
    f32x2 em; em[0] = (EC0); em[1] = (EC1);                                    \
    const f32x2 su = tanh2(em + cs * ctx + hid);                               \
    /* window update in regs + SINGLE evict write (row base-2 leaves) */       \
    const f32x2 g  = su * inv;                                                 \
    const f32x2 m0v = nb0 + z0 * g, m1v = nb1 + z1 * g, m2v = nb2 + z2 * g,    \
                m3v = nb3 + z3 * g, m4v = nb4 + z4 * g;                        \
    *(f32x2*)p0 = m0v;                                                         \
    __builtin_amdgcn_sched_barrier(0);  /* pin DS issue ahead of the tree */   \
    /* reduce tree (long latency; LDS + jd-load latencies hide under it) */    \
    float s1 = su[0] + su[1];                                                  \
    const f32x2 sq = su * su;  float s2 = sq[0] + sq[1];                       \
    const f32x2 sg = su * wg;  float s3 = sg[0] + sg[1];                       \
    wave_sum64_x3(s1, s2, s3);                                                 \
    /* carry: rows base-1..base+2 stay dirty in regs; base+3 clean */          \
    baseW = (base + 1) & 255;                                                  \
    ptrW  = ptr + 1.0f; if (ptrW >= 256.0f) ptrW -= 256.0f;                    \
    wnb0 = m1v; wnb1 = m2v; wnb2 = m3v; wnb3 = m4v; wnb4 = wnb4n;              \
    wp0 = p1; wp1 = p2; wp2 = p3; wp3 = p4; wp4 = wp4n;                        \
    jtW_pre = jump_dest[baseW];           /* global load, used next step */    \
    jt_cur  = jt_nxt;                                                          \
    ctxWp = inv * (((wnb0 * z0 + wnb1 * z1) + (wnb2 * z2 + wnb3 * z3))         \
                   + wnb4 * z4);                                               \
    /* LN + gate */                                                            \
    const float mu   = s1 * (1.0f / En);                                       \
    const float var  = s2 * (1.0f / En) - mu * mu;                             \
    const float rstd = __builtin_amdgcn_rsqf(var + LN_EPS);                    \
    hid = (su - mu) * rstd * lnw + lnb;                                        \
    jl  = s3 + bgs;                                                            \
}

    for (int k = 0; k < 64; ++k) {
        #pragma unroll
        for (int g = 0; g < 4; ++g) {
            const int tb  = k * 4 + g;
            int tbn = tb + 1; if (tbn > 255) tbn = 255;
            // prefetch next group: buf[(tbn>>2)%3] is never producer-active
            const float* sb = stg + ((tbn >> 2) % 3) * 2048 + (tbn & 3) * 512 + 4 * l;
            float4 B0 = *(const float4*)sb;
            float4 B1 = *(const float4*)(sb + 256);
            SSTEP(A0.x, A1.x)
            SSTEP(A0.y, A1.y)
            SSTEP(A0.z, A1.z)
            SSTEP(A0.w, A1.w)
            A0 = B0; A1 = B1;
        }
        __syncthreads();               // chunk boundary (chunk k+2 staged)
    }
#undef SSTEP

    // epilogue: logits = hid @ Wo^T + bo
    __builtin_amdgcn_s_setprio(0);
    mem[l] = hid[0]; mem[64 + l] = hid[1];
    __syncthreads();                   // final
    const float4* w4 = (const float4*)(Wo + l * En);
    const float4* h4 = (const float4*)mem;
    float a0 = 0.f, a1 = 0.f, a2 = 0.f, a3 = 0.f;
    #pragma unroll
    for (int i = 0; i < En / 4; ++i) {
        float4 wv = w4[i]; float4 hv = h4[i];
        a0 += wv.x * hv.x; a1 += wv.y * hv.y; a2 += wv.z * hv.z; a3 += wv.w * hv.w;
    }
    out[b * NOUTn + l] = (a0 + a1) + (a2 + a3) + bo[l];
}

extern "C" void kernel_launch(void* const* d_in, const int* in_sizes, int n_in,
                              void* d_out, int out_size, void* d_ws, size_t ws_size,
                              hipStream_t stream) {
    const float* x            = (const float*)d_in[0];
    const float* pointer_init = (const float*)d_in[1];
    const float* W_in         = (const float*)d_in[2];
    const float* b_in         = (const float*)d_in[3];
    const float* ln_w         = (const float*)d_in[4];
    const float* ln_b         = (const float*)d_in[5];
    const float* jump_dest    = (const float*)d_in[6];
    const float* Wg           = (const float*)d_in[7];
    const float* bg           = (const float*)d_in[8];
    const float* cs           = (const float*)d_in[9];
    const float* Wo           = (const float*)d_in[10];
    const float* bo           = (const float*)d_in[11];
    float* out = (float*)d_out;
    (void)d_ws; (void)ws_size;   // zero workspace (ws bytes are billed, R10)

    (void)hipFuncSetAttribute((const void*)fused2_kernel,
                              hipFuncAttributeMaxDynamicSharedMemorySize, LDSF_BYTES);
    fused2_kernel<<<Bn, 192, LDSF_BYTES, stream>>>(
        x, pointer_init, W_in, b_in, ln_w, ln_b, jump_dest, Wg, bg, cs,
        Wo, bo, out);
}

// Round 9
// 471.806 us; speedup vs baseline: 6.0997x; 1.0912x over previous
//
#include <hip/hip_runtime.h>
#include <math.h>

// Problem constants (from reference)
#define Bn    256
#define Tn    1024
#define In    64
#define Pn    256
#define En    128
#define NOUTn 64
#define LN_EPS 1e-5f

// softmax factorization constants (TEMP=8):
// z_j ∝ exp((j-2)*frac/4) * exp(-(j-2)^2/8)  (common exp(-frac^2/8) cancels)
#define C1f 0.3606737602222409f     // log2(e)/4
#define K1f 0.8824969025845955f     // exp(-1/8)
#define K2f 0.6065306597126334f     // exp(-4/8)

typedef float f32x2 __attribute__((ext_vector_type(2)));

__device__ __forceinline__ float tanh_fast(float x) {
    float e = __builtin_amdgcn_exp2f(x * 2.88539008177793f);   // e^(2x)
    return 1.0f - 2.0f * __builtin_amdgcn_rcpf(e + 1.0f);
}
__device__ __forceinline__ f32x2 tanh2(f32x2 x) {
    f32x2 e;
    e[0] = __builtin_amdgcn_exp2f(x[0] * 2.88539008177793f);
    e[1] = __builtin_amdgcn_exp2f(x[1] * 2.88539008177793f);
    f32x2 r;
    r[0] = __builtin_amdgcn_rcpf(e[0] + 1.0f);
    r[1] = __builtin_amdgcn_rcpf(e[1] + 1.0f);
    return 1.0f - 2.0f * r;
}

template<int CTRL, int RMASK>
__device__ __forceinline__ float dpp_add(float x) {
    return x + __int_as_float(__builtin_amdgcn_update_dpp(
        0, __float_as_int(x), CTRL, RMASK, 0xF, false));
}
__device__ __forceinline__ void wave_sum64_x3(float& x, float& y, float& z) {
#define LVL(C, R) x = dpp_add<C, R>(x); y = dpp_add<C, R>(y); z = dpp_add<C, R>(z);
    LVL(0x111, 0xF)
    LVL(0x112, 0xF)
    LVL(0x114, 0xF)
    LVL(0x118, 0xF)
    LVL(0x142, 0xA)
    LVL(0x143, 0xC)
#undef LVL
    x = __int_as_float(__builtin_amdgcn_readlane(__float_as_int(x), 63));
    y = __int_as_float(__builtin_amdgcn_readlane(__float_as_int(y), 63));
    z = __int_as_float(__builtin_amdgcn_readlane(__float_as_int(z), 63));
}

// ===========================================================================
// R17: TAIL-COMMIT UNIFIED STATE. Key fact: jl for step t+1 is known at step
// t's tail -> the branch direction of t+1 is fully determined before t+1
// begins. So all next-step state {CTX, PTR, BASE, NB[5], P[5], Z[5], INV} is
// committed at the tail: the walk-carry (the register shift R12 already did)
// writes it unconditionally; ONE tail branch overwrites it on jump-next
// (gather issued after this step's scatter -> in-order DS pipe makes it
// bit-identical to R12's in-branch gather). The step TOP is branch-free:
// su = tanh2(em + cs*CTX + hid) issues immediately.
//   - removes the per-step top branch + 12-way select from the chain
//   - jump gather starts ~150cy earlier (at t's tail, not after t+1's gate)
//   - jd[BASE] readable at top (BASE final at prev tail) -> single jt value
//   - wnb4n + jd reads at top, AHEAD of the scatter in DS queue order
// No sched_barrier (R16 lesson), jd in LDS (not global), full 5-write
// scatter. Producers/staging/epilogue byte-identical to R12 (392us best).
// LDS: ring 128 KB + jd 1 KB + stage 3x8 KB = 153 KB.
// ===========================================================================
#define STAGE_FLOATS (3 * 16 * En)                 // 6144
#define LDSF_FLOATS  (Pn * En + Pn + STAGE_FLOATS) // 39168
#define LDSF_BYTES   (LDSF_FLOATS * 4)             // 156672

__global__ __launch_bounds__(192, 1)
void fused2_kernel(const float* __restrict__ x,
                   const float* __restrict__ pointer_init,
                   const float* __restrict__ W_in, const float* __restrict__ b_in,
                   const float* __restrict__ ln_w, const float* __restrict__ ln_b,
                   const float* __restrict__ jump_dest,
                   const float* __restrict__ Wg,  const float* __restrict__ bg,
                   const float* __restrict__ cs_ptr,
                   const float* __restrict__ Wo,  const float* __restrict__ bo,
                   float* __restrict__ out) {
    extern __shared__ float lds[];
    float* mem = lds;                    // ring: [row][2*l + c]
    float* jd  = lds + Pn * En;          // jump_dest copy
    float* stg = lds + Pn * En + Pn;     // stage: [buf3][tq4][e128][t4]

    const int b   = blockIdx.x;
    const int tid = threadIdx.x;

    if (tid >= 64) {
        // ================= PRODUCERS (waves 1,2): 4t x 4e register tile ======
        const int p    = tid - 64;        // 0..127
        const int tq   = p >> 5;          // 0..3 : which 4-t group of the chunk
        const int eidx = p & 31;          // e = eidx + 32*j, j=0..3
        float be[4];
        #pragma unroll
        for (int j = 0; j < 4; ++j) be[j] = b_in[eidx + 32 * j];
        const float* xb = x + (size_t)b * Tn * In;

#define PRODUCE(K, BUF) {                                                     \
    const int t0 = (K) * 16 + tq * 4;                                         \
    const float4* xr = (const float4*)(xb + t0 * In);   /* per-lane addr */   \
    float acc[4][4];                                                          \
    _Pragma("unroll")                                                         \
    for (int tt = 0; tt < 4; ++tt)                                            \
        _Pragma("unroll")                                                     \
        for (int j = 0; j < 4; ++j) acc[tt][j] = 0.f;                         \
    _Pragma("unroll")                                                         \
    for (int i4 = 0; i4 < 16; ++i4) {                                         \
        float4 xv[4];                                                         \
        _Pragma("unroll")                                                     \
        for (int tt = 0; tt < 4; ++tt) xv[tt] = xr[tt * 16 + i4];             \
        float4 wf[4];                                                         \
        _Pragma("unroll")                                                     \
        for (int j = 0; j < 4; ++j)                                           \
            wf[j] = *(const float4*)(W_in + (eidx + 32 * j) * In + i4 * 4);   \
        _Pragma("unroll")                                                     \
        for (int tt = 0; tt < 4; ++tt)                                        \
            _Pragma("unroll")                                                 \
            for (int j = 0; j < 4; ++j) {                                     \
                acc[tt][j] += xv[tt].x * wf[j].x;                             \
                acc[tt][j] += xv[tt].y * wf[j].y;                             \
                acc[tt][j] += xv[tt].z * wf[j].z;                             \
                acc[tt][j] += xv[tt].w * wf[j].w;                             \
            }                                                                 \
    }                                                                         \
    float* sg = stg + (BUF) * 2048 + tq * 512;                                \
    _Pragma("unroll")                                                         \
    for (int j = 0; j < 4; ++j) {                                             \
        float4 o;                                                             \
        o.x = tanh_fast(acc[0][j] + be[j]);                                   \
        o.y = tanh_fast(acc[1][j] + be[j]);                                   \
        o.z = tanh_fast(acc[2][j] + be[j]);                                   \
        o.w = tanh_fast(acc[3][j] + be[j]);                                   \
        *(float4*)(sg + (eidx + 32 * j) * 4) = o;                             \
    }                                                                         \
}
        PRODUCE(0, 0)
        PRODUCE(1, 1)
        __syncthreads();                   // #1: chunks 0,1 staged
        int buf = 2;
        for (int k = 0; k < 64; ++k) {
            if (k + 2 < 64) {
                PRODUCE(k + 2, buf)
                buf = (buf == 2) ? 0 : buf + 1;
            }
            __syncthreads();               // chunk boundary
        }
#undef PRODUCE
        __syncthreads();                   // final: hid broadcast
        return;
    }

    // ================= CONSUMER (wave 0): tail-commit scan ==================
    const int l = tid;

    float4* m4 = (float4*)mem;
    for (int i = l; i < Pn * En / 4; i += 64) m4[i] = make_float4(0.f, 0.f, 0.f, 0.f);
    for (int i = l; i < Pn; i += 64) jd[i] = jump_dest[i];

    const f32x2 lnw = {ln_w[l], ln_w[l + 64]};
    const f32x2 lnb = {ln_b[l], ln_b[l + 64]};
    const f32x2 wg  = {Wg[l],   Wg[l + 64]};
    const float bgs = bg[0];
    const float cs  = 1.0f / (1.0f + expf(-cs_ptr[0]));
    f32x2 hid = {0.f, 0.f};
    float jl;

    // ---- unified state, committed for the UPCOMING step ----
    // prologue = the jump-commit run once from pointer_init (mem is zeroed,
    // so the gather returns 0s and CTX = 0, bit-identical to R12's step 0).
    float PTR = pointer_init[b];
    int   it0 = (int)PTR;  int BASE = it0 > 255 ? 255 : it0;
    float *P0 = mem + (((BASE + 254) & 255) << 7) + 2 * l;
    float *P1 = mem + (((BASE + 255) & 255) << 7) + 2 * l;
    float *P2 = mem + (BASE << 7) + 2 * l;
    float *P3 = mem + (((BASE + 1) & 255) << 7) + 2 * l;
    float *P4 = mem + (((BASE + 2) & 255) << 7) + 2 * l;
    float Z0, Z1, Z2 = 1.0f, Z3, Z4, INV;
    {
        const float frac = PTR - (float)BASE;
        const float r  = __builtin_amdgcn_exp2f(frac * C1f);
        const float ri = __builtin_amdgcn_exp2f(-frac * C1f);
        Z0 = K2f * ri * ri; Z1 = K1f * ri;
        Z3 = K1f * r;       Z4 = K2f * r * r;
        INV = __builtin_amdgcn_rcpf(((Z0 + Z1) + (Z2 + Z3)) + Z4);
    }

    __syncthreads();                       // #1: mem zeroed, jd, stage 0,1
    __builtin_amdgcn_s_setprio(1);         // favor the serial wave

    f32x2 NB0 = *(f32x2*)P0, NB1 = *(f32x2*)P1, NB2 = *(f32x2*)P2,
          NB3 = *(f32x2*)P3, NB4 = *(f32x2*)P4;
    f32x2 CTX = INV * (((NB0 * Z0 + NB1 * Z1) + (NB2 * Z2 + NB3 * Z3))
                       + NB4 * Z4);

    // A = current 4-step group registers (group tb=0)
    const float* sa0 = stg + 4 * l;        // buf0, group 0, ch l
    float4 A0 = *(const float4*)sa0;
    float4 A1 = *(const float4*)(sa0 + 256);

#define SSTEP(EC0, EC1) {                                                      \
    /* branch-free top: early DS reads (ahead of the scatter in queue) */      \
    float* wp4n = mem + (((BASE + 3) & 255) << 7) + 2 * l;                     \
    const f32x2 wnb4n  = *(f32x2*)wp4n;                                        \
    const float JTnext = jd[BASE];    /* jump target if next step jumps */     \
    f32x2 em; em[0] = (EC0); em[1] = (EC1);                                    \
    const f32x2 su = tanh2(em + cs * CTX + hid);                               \
    /* reduce tree (long latency; scatter + carry issue under it) */           \
    float s1 = su[0] + su[1];                                                  \
    const f32x2 sq = su * su;  float s2 = sq[0] + sq[1];                       \
    const f32x2 sg = su * wg;  float s3 = sg[0] + sg[1];                       \
    wave_sum64_x3(s1, s2, s3);                                                 \
    /* memory update (identical math) */                                       \
    const f32x2 g  = su * INV;                                                 \
    const f32x2 m0v = NB0 + Z0 * g, m1v = NB1 + Z1 * g, m2v = NB2 + Z2 * g,    \
                m3v = NB3 + Z3 * g, m4v = NB4 + Z4 * g;                        \
    *(f32x2*)P0 = m0v; *(f32x2*)P1 = m1v; *(f32x2*)P2 = m2v;                   \
    *(f32x2*)P3 = m3v; *(f32x2*)P4 = m4v;                                      \
    /* unconditional walk-carry into the unified state regs */                 \
    PTR = PTR + 1.0f; if (PTR >= 256.0f) PTR -= 256.0f;                        \
    BASE = (BASE + 1) & 255;                                                   \
    NB0 = m1v; NB1 = m2v; NB2 = m3v; NB3 = m4v; NB4 = wnb4n;                   \
    P0 = P1; P1 = P2; P2 = P3; P3 = P4; P4 = wp4n;                             \
    CTX = INV * (((NB0 * Z0 + NB1 * Z1) + (NB2 * Z2 + NB3 * Z3))               \
                 + NB4 * Z4);                                                  \
    /* LN + gate */                                                            \
    const float mu   = s1 * (1.0f / En);                                       \
    const float var  = s2 * (1.0f / En) - mu * mu;                             \
    const float rstd = __builtin_amdgcn_rsqf(var + LN_EPS);                    \
    hid = (su - mu) * rstd * lnw + lnb;                                        \
    jl  = s3 + bgs;                                                            \
    /* tail commit: overwrite state iff next step is a JUMP. Gather is       \
       issued after this step's scatter -> in-order DS pipe returns exactly   \
       what R12's in-branch gather would read. */                              \
    if (__builtin_amdgcn_readfirstlane(__float_as_int(jl)) > 0) {              \
        PTR = JTnext;                                                          \
        int ib = (int)PTR; BASE = ib > 255 ? 255 : ib;                         \
        P0 = mem + (((BASE + 254) & 255) << 7) + 2 * l;                        \
        P1 = mem + (((BASE + 255) & 255) << 7) + 2 * l;                        \
        P2 = mem + (BASE << 7) + 2 * l;                                        \
        P3 = mem + (((BASE + 1) & 255) << 7) + 2 * l;                          \
        P4 = mem + (((BASE + 2) & 255) << 7) + 2 * l;                          \
        NB0 = *(f32x2*)P0; NB1 = *(f32x2*)P1; NB2 = *(f32x2*)P2;               \
        NB3 = *(f32x2*)P3; NB4 = *(f32x2*)P4;                                  \
        const float frac = PTR - (float)BASE;                                  \
        const float r  = __builtin_amdgcn_exp2f(frac * C1f);                   \
        const float ri = __builtin_amdgcn_exp2f(-frac * C1f);                  \
        Z0 = K2f * ri * ri; Z1 = K1f * ri; Z2 = 1.0f;                          \
        Z3 = K1f * r;       Z4 = K2f * r * r;                                  \
        INV = __builtin_amdgcn_rcpf(((Z0 + Z1) + (Z2 + Z3)) + Z4);             \
        CTX = INV * (((NB0 * Z0 + NB1 * Z1) + (NB2 * Z2 + NB3 * Z3))           \
                     + NB4 * Z4);                                              \
    }                                                                          \
}

    for (int k = 0; k < 64; ++k) {
        #pragma unroll
        for (int g = 0; g < 4; ++g) {
            const int tb  = k * 4 + g;
            int tbn = tb + 1; if (tbn > 255) tbn = 255;
            // prefetch next group: buf[(tbn>>2)%3] is never producer-active
            const float* sb = stg + ((tbn >> 2) % 3) * 2048 + (tbn & 3) * 512 + 4 * l;
            float4 B0 = *(const float4*)sb;
            float4 B1 = *(const float4*)(sb + 256);
            SSTEP(A0.x, A1.x)
            SSTEP(A0.y, A1.y)
            SSTEP(A0.z, A1.z)
            SSTEP(A0.w, A1.w)
            A0 = B0; A1 = B1;
        }
        __syncthreads();               // chunk boundary (chunk k+2 staged)
    }
#undef SSTEP

    // epilogue: logits = hid @ Wo^T + bo
    __builtin_amdgcn_s_setprio(0);
    mem[l] = hid[0]; mem[64 + l] = hid[1];
    __syncthreads();                   // final
    const float4* w4 = (const float4*)(Wo + l * En);
    const float4* h4 = (const float4*)mem;
    float a0 = 0.f, a1 = 0.f, a2 = 0.f, a3 = 0.f;
    #pragma unroll
    for (int i = 0; i < En / 4; ++i) {
        float4 wv = w4[i]; float4 hv = h4[i];
        a0 += wv.x * hv.x; a1 += wv.y * hv.y; a2 += wv.z * hv.z; a3 += wv.w * hv.w;
    }
    out[b * NOUTn + l] = (a0 + a1) + (a2 + a3) + bo[l];
}

extern "C" void kernel_launch(void* const* d_in, const int* in_sizes, int n_in,
                              void* d_out, int out_size, void* d_ws, size_t ws_size,
                              hipStream_t stream) {
    const float* x            = (const float*)d_in[0];
    const float* pointer_init = (const float*)d_in[1];
    const float* W_in         = (const float*)d_in[2];
    const float* b_in         = (const float*)d_in[3];
    const float* ln_w         = (const float*)d_in[4];
    const float* ln_b         = (const float*)d_in[5];
    const float* jump_dest    = (const float*)d_in[6];
    const float* Wg           = (const float*)d_in[7];
    const float* bg           = (const float*)d_in[8];
    const float* cs           = (const float*)d_in[9];
    const float* Wo           = (const float*)d_in[10];
    const float* bo           = (const float*)d_in[11];
    float* out = (float*)d_out;
    (void)d_ws; (void)ws_size;   // zero workspace (ws bytes are billed, R10)

    (void)hipFuncSetAttribute((const void*)fused2_kernel,
                              hipFuncAttributeMaxDynamicSharedMemorySize, LDSF_BYTES);
    fused2_kernel<<<Bn, 192, LDSF_BYTES, stream>>>(
        x, pointer_init, W_in, b_in, ln_w, ln_b, jump_dest, Wg, bg, cs,
        Wo, bo, out);
}